// Round 15
// baseline (403.039 us; speedup 1.0000x reference)
//
#include <hip/hip_runtime.h>
#include <math.h>

#define NVEC 32768   // 32*32*32 vectors
#define NE   1024    // codebook entries
#define ED   64      // embedding dim
#define TOT  2097152 // NVEC*ED total z elements
#define NCHUNK 8     // code chunks inside k_dist
#define CHUNK  128   // codes per chunk
#define MT     64    // vectors per k_dist block

// d_out offsets (in floats): loss | z_q_st | perplexity | min_encodings | idx
#define O_LOSS   0
#define O_ZQ     1
#define O_PERP   2097153
#define O_MINENC 2097154
#define O_IDX    35651586

// d_ws offsets (in floats). No ws memset: every cell read has a producer
// (the k_zq ticket counter is zeroed by k_ema, which runs earlier in-stream).
#define W_PIDX   0        // [32768] final idx (int), written by k_dist
#define W_CS     32768    // [1024]
#define W_SUMENC 33792    // [1024*64]
#define W_NEWEMB 99328    // [1024*64]
#define W_LOSSP  164864   // [2048]
#define W_TICKET 166912   // int ticket counter for fused loss reduction

// R14 post-mortem: all kernels below the 85 µs harness-fill floor; k_dist
// ~55 µs vs 27 µs FMA floor. Two overheads removed here: (1) per-chunk
// global staging was on the critical path -> software-pipelined (pf[8]
// register prefetch of chunk q+1 during chunk q compute); (2) per-chunk
// esq recompute (half-wave, serialized) -> all 1024 esq once at block
// start (same pairwise formula per code -> bit-identical values).
__global__ void __launch_bounds__(256, 3) k_dist(const float* __restrict__ z,
                                                 const float* __restrict__ emb,
                                                 int* __restrict__ fidx,
                                                 float* __restrict__ out) {
    __shared__ __align__(16) float s_a[64 * 64];    // [c][m] : 2*z (16 KB)
    __shared__ __align__(16) float s_b[64 * 132];   // [c][k-swizzled] (33 KB)
    __shared__ float s_esq[NE];                     // all 1024 ||e||^2 (4 KB)
    __shared__ float s_zsq[MT];

    int tid = threadIdx.x;
    int n0 = blockIdx.x * MT;
    int b = n0 >> 10, hw0 = n0 & 1023;  // MT=64 tile never crosses a b boundary
    const float* zb = z + b * 65536 + hw0;

    // Stage A once: 64c x 64m = 1024 float4, coalesced; store 2*z (exact x2)
#pragma unroll
    for (int j = 0; j < 4; ++j) {
        int f4i = j * 256 + tid;
        int c = f4i >> 4, pos = (f4i & 15) * 4;
        float4 v = *(const float4*)(zb + (c << 10) + pos);
        v.x = __fmul_rn(2.0f, v.x);
        v.y = __fmul_rn(2.0f, v.y);
        v.z = __fmul_rn(2.0f, v.z);
        v.w = __fmul_rn(2.0f, v.w);
        *(float4*)(s_a + c * 64 + pos) = v;
    }
    // All 1024 esq once (np-pairwise, 4 codes/thread); emb is L2-hot.
#pragma unroll
    for (int j = 0; j < 4; ++j) {
        int k = j * 256 + tid;
        const float* ep = emb + (size_t)k * ED;
        float r[8];
#pragma unroll
        for (int u = 0; u < 8; ++u) r[u] = __fmul_rn(ep[u], ep[u]);
#pragma unroll
        for (int i = 8; i < 64; i += 8)
#pragma unroll
            for (int u = 0; u < 8; ++u)
                r[u] = __fadd_rn(r[u], __fmul_rn(ep[i + u], ep[i + u]));
        s_esq[k] = __fadd_rn(
            __fadd_rn(__fadd_rn(r[0], r[1]), __fadd_rn(r[2], r[3])),
            __fadd_rn(__fadd_rn(r[4], r[5]), __fadd_rn(r[6], r[7])));
    }
    __syncthreads();

    // zsq once (threads 0..63): np-pairwise over z; from (2z): exact x0.25.
    if (tid < MT) {
        float r[8];
#pragma unroll
        for (int j = 0; j < 8; ++j) {
            float v = s_a[j * 64 + tid];
            r[j] = __fmul_rn(v, v);
        }
#pragma unroll
        for (int i = 8; i < 64; i += 8)
#pragma unroll
            for (int j = 0; j < 8; ++j) {
                float v = s_a[(i + j) * 64 + tid];
                r[j] = __fadd_rn(r[j], __fmul_rn(v, v));
            }
        s_zsq[tid] = __fmul_rn(0.25f, __fadd_rn(
            __fadd_rn(__fadd_rn(r[0], r[1]), __fadd_rn(r[2], r[3])),
            __fadd_rn(__fadd_rn(r[4], r[5]), __fadd_rn(r[6], r[7]))));
    }
    __syncthreads();

    int mi = tid & 15, ki = tid >> 4;
    int mbase = mi * 4, kbase = ki * 8;
    float zs[4];
#pragma unroll
    for (int mu = 0; mu < 4; ++mu) zs[mu] = s_zsq[mbase + mu];

    float bd[4];
    int bix[4];
#pragma unroll
    for (int mu = 0; mu < 4; ++mu) { bd[mu] = 3.4e38f; bix[mu] = kbase; }

    // This thread's staging slice: 8 float4s per chunk (f4i = j*256+tid).
    int s_kl[8], s_c4[8];
#pragma unroll
    for (int j = 0; j < 8; ++j) {
        int f4i = j * 256 + tid;
        s_kl[j] = f4i >> 4;
        s_c4[j] = f4i & 15;
    }

    // Prefetch chunk 0.
    float4 pf[8];
#pragma unroll
    for (int j = 0; j < 8; ++j)
        pf[j] = *(const float4*)(emb + (size_t)s_kl[j] * ED + s_c4[j] * 4);

    for (int q = 0; q < NCHUNK; ++q) {
        __syncthreads();  // previous chunk's readers of s_b are done
        // Store prefetched B transposed+swizzled: phys quad (k4+c4)&31.
#pragma unroll
        for (int j = 0; j < 8; ++j) {
            int kl = s_kl[j], c4 = s_c4[j];
            int base = (((kl >> 2) + c4) & 31) * 4 + (kl & 3);
            s_b[(c4 * 4 + 0) * 132 + base] = pf[j].x;
            s_b[(c4 * 4 + 1) * 132 + base] = pf[j].y;
            s_b[(c4 * 4 + 2) * 132 + base] = pf[j].z;
            s_b[(c4 * 4 + 3) * 132 + base] = pf[j].w;
        }
        // Issue next chunk's loads now; waitcnt lands at next iteration's
        // stores — latency overlapped with this chunk's compute.
        if (q + 1 < NCHUNK) {
            const float* nb = emb + (size_t)(q + 1) * CHUNK * ED;
#pragma unroll
            for (int j = 0; j < 8; ++j)
                pf[j] = *(const float4*)(nb + (size_t)s_kl[j] * ED + s_c4[j] * 4);
        }
        __syncthreads();  // staging visible

        int k0 = q * CHUNK;
        float acc[4][8];
#pragma unroll
        for (int mu = 0; mu < 4; ++mu)
#pragma unroll
            for (int ku = 0; ku < 8; ++ku) acc[mu][ku] = 0.f;

#pragma unroll 4
        for (int c = 0; c < 64; ++c) {
            int c4 = c >> 2;
            float4 av = *(const float4*)(s_a + c * 64 + mbase);
            float4 b0 = *(const float4*)(s_b + c * 132 + ((2 * ki + c4) & 31) * 4);
            float4 b1 = *(const float4*)(s_b + c * 132 + ((2 * ki + 1 + c4) & 31) * 4);
#pragma unroll
            for (int mu = 0; mu < 4; ++mu) {
                float a = (&av.x)[mu];
                acc[mu][0] = __fmaf_rn(a, b0.x, acc[mu][0]);
                acc[mu][1] = __fmaf_rn(a, b0.y, acc[mu][1]);
                acc[mu][2] = __fmaf_rn(a, b0.z, acc[mu][2]);
                acc[mu][3] = __fmaf_rn(a, b0.w, acc[mu][3]);
                acc[mu][4] = __fmaf_rn(a, b1.x, acc[mu][4]);
                acc[mu][5] = __fmaf_rn(a, b1.y, acc[mu][5]);
                acc[mu][6] = __fmaf_rn(a, b1.z, acc[mu][6]);
                acc[mu][7] = __fmaf_rn(a, b1.w, acc[mu][7]);
            }
        }

        // d = fl(fl(zsq+esq) - dot2); running per-thread argmin (k ascending)
#pragma unroll
        for (int mu = 0; mu < 4; ++mu)
#pragma unroll
            for (int ku = 0; ku < 8; ++ku) {
                float d = __fsub_rn(__fadd_rn(zs[mu], s_esq[k0 + kbase + ku]),
                                    acc[mu][ku]);
                if (d < bd[mu]) { bd[mu] = d; bix[mu] = k0 + kbase + ku; }
            }
    }

    // Merge 16 ki candidates per m with lexicographic (d, i) min ==
    // np.argmin lowest-index-among-minima. Reuse s_b as scratch.
    __syncthreads();
    float* red_d = s_b;               // [16][64]
    int* red_i = (int*)(s_b + 1024);  // [16][64]
#pragma unroll
    for (int mu = 0; mu < 4; ++mu) {
        red_d[ki * 64 + mbase + mu] = bd[mu];
        red_i[ki * 64 + mbase + mu] = bix[mu];
    }
    __syncthreads();
    if (tid < MT) {
        float best = red_d[tid];
        int bi = red_i[tid];
#pragma unroll
        for (int q = 1; q < 16; ++q) {
            float d = red_d[q * 64 + tid];
            int i = red_i[q * 64 + tid];
            if (d < best || (d == best && i < bi)) { best = d; bi = i; }
        }
        fidx[n0 + tid] = bi;
        out[O_IDX + n0 + tid] = (float)bi;
    }
}

// Gather-based segment sum: one block per code k, 4 waves. Ballot-scan idx;
// members accumulated lane=element; popcount -> cs. Deterministic. No atomics.
__global__ void __launch_bounds__(256) k_sumenc(const int* __restrict__ idx,
                                                const float* __restrict__ z,
                                                float* __restrict__ cs,
                                                float* __restrict__ sumenc) {
    int k = blockIdx.x;
    int wave = threadIdx.x >> 6, lane = threadIdx.x & 63;
    float acc = 0.f;
    int cnt = 0;
    int base = wave * 8192;
    for (int it = 0; it < 128; ++it) {
        int n0 = base + it * 64;
        int idv = idx[n0 + lane];
        unsigned long long m = __ballot(idv == k);
        cnt += __popcll(m);
        while (m) {
            int bit = __ffsll((unsigned long long)m) - 1;  // ascending n
            m &= m - 1;
            int n = n0 + bit;
            int b = n >> 10, hw = n & 1023;
            acc = __fadd_rn(acc, z[b * 65536 + lane * 1024 + hw]);  // element c = lane
        }
    }
    __shared__ float sacc[4][64];
    __shared__ int scnt[4];
    sacc[wave][lane] = acc;
    if (lane == 0) scnt[wave] = cnt;
    __syncthreads();
    if (wave == 0) {
        float t = __fadd_rn(__fadd_rn(sacc[0][lane], sacc[1][lane]),
                            __fadd_rn(sacc[2][lane], sacc[3][lane]));
        sumenc[k * ED + lane] = t;
        if (lane == 0) cs[k] = (float)(scnt[0] + scnt[1] + scnt[2] + scnt[3]);
    }
}

// Single block, 1024 threads: EMA cluster-size + ntot/entropy reductions +
// perplexity + codebook update. Also zeroes the k_zq ticket counter (stream
// order guarantees visibility to the later k_zq dispatch).
__global__ void __launch_bounds__(1024) k_ema(const float* __restrict__ ema_cs,
                                              const float* __restrict__ ema_w,
                                              const float* __restrict__ cs,
                                              const float* __restrict__ sumenc,
                                              float* __restrict__ newemb,
                                              int* __restrict__ ticket,
                                              float* __restrict__ out) {
    int k = threadIdx.x;  // 0..1023 == NE
    if (k == 0) *ticket = 0;
    float c = cs[k];
    float ncs = 0.99f * ema_cs[k] + (1.0f - 0.99f) * c;
    float p = c * (1.0f / (float)NVEC);
    float e = p * logf(p + 1e-10f);
    float rn_ = ncs, re_ = e;
#pragma unroll
    for (int o = 32; o > 0; o >>= 1) {
        rn_ += __shfl_down(rn_, o, 64);
        re_ += __shfl_down(re_, o, 64);
    }
    __shared__ float sn[16], se_[16];
    __shared__ float s_n;
    int wave = k >> 6, lane = k & 63;
    if (lane == 0) { sn[wave] = rn_; se_[wave] = re_; }
    __syncthreads();
    if (k == 0) {
        float tn = 0.f, te = 0.f;
#pragma unroll
        for (int w = 0; w < 16; ++w) { tn += sn[w]; te += se_[w]; }
        s_n = tn;
        out[O_PERP] = expf(-te);
    }
    __syncthreads();
    float nt = s_n;
    float csn = (ncs + 1e-5f) / (nt + 1024.0f * 1e-5f) * nt;
    __shared__ float s_csn[NE];
    s_csn[k] = csn;
    __syncthreads();
    for (int t = k; t < NE * ED; t += 1024) {  // coalesced
        float nw = 0.99f * ema_w[t] + (1.0f - 0.99f) * sumenc[t];
        newemb[t] = nw / s_csn[t >> 6];
    }
}

// 2048 blocks x 256 threads: z_q + straight-through + loss partials + one-hot
// rows (16/block, full 0..1023 coverage) + FUSED final loss reduction via
// threadfence-ticket (last block re-reduces lossp with k_fin's exact order).
__global__ void __launch_bounds__(256) k_zq(const float* __restrict__ z,
                                            const int* __restrict__ idx,
                                            const float* __restrict__ newemb,
                                            float* __restrict__ out,
                                            float* __restrict__ lossp,
                                            int* __restrict__ ticket) {
    __shared__ int sbi[16];
    if (threadIdx.x < 16) sbi[threadIdx.x] = idx[blockIdx.x * 16 + threadIdx.x];
    __syncthreads();

    float local = 0.f;
#pragma unroll
    for (int i = 0; i < 4; ++i) {
        int t = blockIdx.x * 256 + threadIdx.x + i * 524288;
        int b = t >> 16, c = (t >> 10) & 63, hw = t & 1023;
        int n = (b << 10) | hw;
        float e = newemb[idx[n] * ED + c];
        float zv = z[t];
        float diff = e - zv;             // z_q - z
        out[O_ZQ + t] = zv + diff;       // straight-through: z + (z_q - z)
        local = fmaf(diff, diff, local);
    }

    // one-hot rows r0..r0+15 (row base ≡ 2 mod 4 floats; full coverage)
    int t = threadIdx.x;
    int r0 = blockIdx.x * 16;
    for (int r = 0; r < 16; ++r) {
        int rbi = sbi[r];
        float* rp = out + O_MINENC + (size_t)(r0 + r) * NE;
        if (t < 254) {
            int col = 2 + t * 4;
            float4 v;
            v.x = (col == rbi) ? 1.0f : 0.0f;
            v.y = (col + 1 == rbi) ? 1.0f : 0.0f;
            v.z = (col + 2 == rbi) ? 1.0f : 0.0f;
            v.w = (col + 3 == rbi) ? 1.0f : 0.0f;
            *(float4*)(rp + col) = v;
        } else if (t == 254) {
            float2 v;
            v.x = (0 == rbi) ? 1.0f : 0.0f;
            v.y = (1 == rbi) ? 1.0f : 0.0f;
            *(float2*)(rp) = v;
        } else {
            float4 v;
            v.x = (1018 == rbi) ? 1.0f : 0.0f;
            v.y = (1019 == rbi) ? 1.0f : 0.0f;
            v.z = (1020 == rbi) ? 1.0f : 0.0f;
            v.w = (1021 == rbi) ? 1.0f : 0.0f;
            *(float4*)(rp + 1018) = v;
            float2 w;
            w.x = (1022 == rbi) ? 1.0f : 0.0f;
            w.y = (1023 == rbi) ? 1.0f : 0.0f;
            *(float2*)(rp + 1022) = w;
        }
    }

#pragma unroll
    for (int o = 32; o > 0; o >>= 1) local += __shfl_down(local, o, 64);
    __shared__ float sp[4];
    int wave = threadIdx.x >> 6;
    if ((threadIdx.x & 63) == 0) sp[wave] = local;
    __syncthreads();
    __shared__ int s_last;
    if (threadIdx.x == 0) {
        lossp[blockIdx.x] = (sp[0] + sp[1]) + (sp[2] + sp[3]);
        __threadfence();  // release: partial visible before ticket
        s_last = (atomicAdd(ticket, 1) == 2047);
    }
    __syncthreads();
    if (s_last) {  // last block: k_fin's exact summation order
        __threadfence();  // acquire side
        float v = 0.f;
#pragma unroll
        for (int i = 0; i < 8; ++i) v += lossp[i * 256 + threadIdx.x];
#pragma unroll
        for (int o = 32; o > 0; o >>= 1) v += __shfl_down(v, o, 64);
        __shared__ float sq[4];
        if ((threadIdx.x & 63) == 0) sq[wave] = v;
        __syncthreads();
        if (threadIdx.x == 0)
            out[O_LOSS] = 0.25f * (((sq[0] + sq[1]) + (sq[2] + sq[3])) *
                                   (1.0f / (float)TOT));
    }
}

extern "C" void kernel_launch(void* const* d_in, const int* in_sizes, int n_in,
                              void* d_out, int out_size, void* d_ws, size_t ws_size,
                              hipStream_t stream) {
    const float* z      = (const float*)d_in[0];
    const float* emb    = (const float*)d_in[1];
    const float* ema_cs = (const float*)d_in[2];
    const float* ema_w  = (const float*)d_in[3];
    float* out = (float*)d_out;
    float* ws  = (float*)d_ws;

    k_dist<<<512, 256, 0, stream>>>(z, emb, (int*)(ws + W_PIDX), out);
    k_sumenc<<<NE, 256, 0, stream>>>((const int*)(ws + W_PIDX), z, ws + W_CS,
                                     ws + W_SUMENC);
    k_ema<<<1, 1024, 0, stream>>>(ema_cs, ema_w, ws + W_CS, ws + W_SUMENC,
                                  ws + W_NEWEMB, (int*)(ws + W_TICKET), out);
    k_zq<<<2048, 256, 0, stream>>>(z, (const int*)(ws + W_PIDX), ws + W_NEWEMB, out,
                                   ws + W_LOSSP, (int*)(ws + W_TICKET));
}

// Round 16
// 298.634 us; speedup vs baseline: 1.3496x; 1.3496x over previous
//
#include <hip/hip_runtime.h>
#include <math.h>

#define NVEC 32768   // 32*32*32 vectors
#define NE   1024    // codebook entries
#define ED   64      // embedding dim
#define TOT  2097152 // NVEC*ED total z elements
#define NCHUNK 8     // code chunks inside k_dist
#define CHUNK  128   // codes per chunk
#define MT     64    // vectors per k_dist block

// d_out offsets (in floats): loss | z_q_st | perplexity | min_encodings | idx
#define O_LOSS   0
#define O_ZQ     1
#define O_PERP   2097153
#define O_MINENC 2097154
#define O_IDX    35651586

// d_ws offsets (in floats). No ws memset: every cell read has a producer.
#define W_PIDX   0        // [32768] final idx (int), written by k_dist
#define W_CS     32768    // [1024]
#define W_SUMENC 33792    // [1024*64]
#define W_NEWEMB 99328    // [1024*64]
#define W_LOSSP  164864   // [2048]

// R15 post-mortem: fusing k_fin into k_zq via __threadfence()+ticket cost
// +115 µs — on gfx950 a device-scope release fence forces an L2 WRITEBACK
// (per-XCD L2s are non-coherent), so all 2048 blocks flush-serialized their
// ~70 KB of dirty one-hot stores (k_zq 28 -> 143 µs @ 1 TB/s). REVERTED to
// the separate 3 µs k_fin dispatch. NEVER put a device-scope fence in a
// store-heavy kernel on CDNA4. k_dist keeps R15's pipeline (neutral+).
__global__ void __launch_bounds__(256, 3) k_dist(const float* __restrict__ z,
                                                 const float* __restrict__ emb,
                                                 int* __restrict__ fidx,
                                                 float* __restrict__ out) {
    __shared__ __align__(16) float s_a[64 * 64];    // [c][m] : 2*z (16 KB)
    __shared__ __align__(16) float s_b[64 * 132];   // [c][k-swizzled] (33 KB)
    __shared__ float s_esq[NE];                     // all 1024 ||e||^2 (4 KB)
    __shared__ float s_zsq[MT];

    int tid = threadIdx.x;
    int n0 = blockIdx.x * MT;
    int b = n0 >> 10, hw0 = n0 & 1023;  // MT=64 tile never crosses a b boundary
    const float* zb = z + b * 65536 + hw0;

    // Stage A once: 64c x 64m = 1024 float4, coalesced; store 2*z (exact x2)
#pragma unroll
    for (int j = 0; j < 4; ++j) {
        int f4i = j * 256 + tid;
        int c = f4i >> 4, pos = (f4i & 15) * 4;
        float4 v = *(const float4*)(zb + (c << 10) + pos);
        v.x = __fmul_rn(2.0f, v.x);
        v.y = __fmul_rn(2.0f, v.y);
        v.z = __fmul_rn(2.0f, v.z);
        v.w = __fmul_rn(2.0f, v.w);
        *(float4*)(s_a + c * 64 + pos) = v;
    }
    // All 1024 esq once (np-pairwise, 4 codes/thread); emb is L2-hot.
#pragma unroll
    for (int j = 0; j < 4; ++j) {
        int k = j * 256 + tid;
        const float* ep = emb + (size_t)k * ED;
        float r[8];
#pragma unroll
        for (int u = 0; u < 8; ++u) r[u] = __fmul_rn(ep[u], ep[u]);
#pragma unroll
        for (int i = 8; i < 64; i += 8)
#pragma unroll
            for (int u = 0; u < 8; ++u)
                r[u] = __fadd_rn(r[u], __fmul_rn(ep[i + u], ep[i + u]));
        s_esq[k] = __fadd_rn(
            __fadd_rn(__fadd_rn(r[0], r[1]), __fadd_rn(r[2], r[3])),
            __fadd_rn(__fadd_rn(r[4], r[5]), __fadd_rn(r[6], r[7])));
    }
    __syncthreads();

    // zsq once (threads 0..63): np-pairwise over z; from (2z): exact x0.25.
    if (tid < MT) {
        float r[8];
#pragma unroll
        for (int j = 0; j < 8; ++j) {
            float v = s_a[j * 64 + tid];
            r[j] = __fmul_rn(v, v);
        }
#pragma unroll
        for (int i = 8; i < 64; i += 8)
#pragma unroll
            for (int j = 0; j < 8; ++j) {
                float v = s_a[(i + j) * 64 + tid];
                r[j] = __fadd_rn(r[j], __fmul_rn(v, v));
            }
        s_zsq[tid] = __fmul_rn(0.25f, __fadd_rn(
            __fadd_rn(__fadd_rn(r[0], r[1]), __fadd_rn(r[2], r[3])),
            __fadd_rn(__fadd_rn(r[4], r[5]), __fadd_rn(r[6], r[7]))));
    }
    __syncthreads();

    int mi = tid & 15, ki = tid >> 4;
    int mbase = mi * 4, kbase = ki * 8;
    float zs[4];
#pragma unroll
    for (int mu = 0; mu < 4; ++mu) zs[mu] = s_zsq[mbase + mu];

    float bd[4];
    int bix[4];
#pragma unroll
    for (int mu = 0; mu < 4; ++mu) { bd[mu] = 3.4e38f; bix[mu] = kbase; }

    // This thread's staging slice: 8 float4s per chunk (f4i = j*256+tid).
    int s_kl[8], s_c4[8];
#pragma unroll
    for (int j = 0; j < 8; ++j) {
        int f4i = j * 256 + tid;
        s_kl[j] = f4i >> 4;
        s_c4[j] = f4i & 15;
    }

    // Prefetch chunk 0.
    float4 pf[8];
#pragma unroll
    for (int j = 0; j < 8; ++j)
        pf[j] = *(const float4*)(emb + (size_t)s_kl[j] * ED + s_c4[j] * 4);

    for (int q = 0; q < NCHUNK; ++q) {
        __syncthreads();  // previous chunk's readers of s_b are done
        // Store prefetched B transposed+swizzled: phys quad (k4+c4)&31.
#pragma unroll
        for (int j = 0; j < 8; ++j) {
            int kl = s_kl[j], c4 = s_c4[j];
            int base = (((kl >> 2) + c4) & 31) * 4 + (kl & 3);
            s_b[(c4 * 4 + 0) * 132 + base] = pf[j].x;
            s_b[(c4 * 4 + 1) * 132 + base] = pf[j].y;
            s_b[(c4 * 4 + 2) * 132 + base] = pf[j].z;
            s_b[(c4 * 4 + 3) * 132 + base] = pf[j].w;
        }
        // Issue next chunk's loads now; latency overlaps this chunk's compute.
        if (q + 1 < NCHUNK) {
            const float* nb = emb + (size_t)(q + 1) * CHUNK * ED;
#pragma unroll
            for (int j = 0; j < 8; ++j)
                pf[j] = *(const float4*)(nb + (size_t)s_kl[j] * ED + s_c4[j] * 4);
        }
        __syncthreads();  // staging visible

        int k0 = q * CHUNK;
        float acc[4][8];
#pragma unroll
        for (int mu = 0; mu < 4; ++mu)
#pragma unroll
            for (int ku = 0; ku < 8; ++ku) acc[mu][ku] = 0.f;

#pragma unroll 4
        for (int c = 0; c < 64; ++c) {
            int c4 = c >> 2;
            float4 av = *(const float4*)(s_a + c * 64 + mbase);
            float4 b0 = *(const float4*)(s_b + c * 132 + ((2 * ki + c4) & 31) * 4);
            float4 b1 = *(const float4*)(s_b + c * 132 + ((2 * ki + 1 + c4) & 31) * 4);
#pragma unroll
            for (int mu = 0; mu < 4; ++mu) {
                float a = (&av.x)[mu];
                acc[mu][0] = __fmaf_rn(a, b0.x, acc[mu][0]);
                acc[mu][1] = __fmaf_rn(a, b0.y, acc[mu][1]);
                acc[mu][2] = __fmaf_rn(a, b0.z, acc[mu][2]);
                acc[mu][3] = __fmaf_rn(a, b0.w, acc[mu][3]);
                acc[mu][4] = __fmaf_rn(a, b1.x, acc[mu][4]);
                acc[mu][5] = __fmaf_rn(a, b1.y, acc[mu][5]);
                acc[mu][6] = __fmaf_rn(a, b1.z, acc[mu][6]);
                acc[mu][7] = __fmaf_rn(a, b1.w, acc[mu][7]);
            }
        }

        // d = fl(fl(zsq+esq) - dot2); running per-thread argmin (k ascending)
#pragma unroll
        for (int mu = 0; mu < 4; ++mu)
#pragma unroll
            for (int ku = 0; ku < 8; ++ku) {
                float d = __fsub_rn(__fadd_rn(zs[mu], s_esq[k0 + kbase + ku]),
                                    acc[mu][ku]);
                if (d < bd[mu]) { bd[mu] = d; bix[mu] = k0 + kbase + ku; }
            }
    }

    // Merge 16 ki candidates per m with lexicographic (d, i) min ==
    // np.argmin lowest-index-among-minima. Reuse s_b as scratch.
    __syncthreads();
    float* red_d = s_b;               // [16][64]
    int* red_i = (int*)(s_b + 1024);  // [16][64]
#pragma unroll
    for (int mu = 0; mu < 4; ++mu) {
        red_d[ki * 64 + mbase + mu] = bd[mu];
        red_i[ki * 64 + mbase + mu] = bix[mu];
    }
    __syncthreads();
    if (tid < MT) {
        float best = red_d[tid];
        int bi = red_i[tid];
#pragma unroll
        for (int q = 1; q < 16; ++q) {
            float d = red_d[q * 64 + tid];
            int i = red_i[q * 64 + tid];
            if (d < best || (d == best && i < bi)) { best = d; bi = i; }
        }
        fidx[n0 + tid] = bi;
        out[O_IDX + n0 + tid] = (float)bi;
    }
}

// Gather-based segment sum: one block per code k, 4 waves. Ballot-scan idx;
// members accumulated lane=element; popcount -> cs. Deterministic. No atomics.
__global__ void __launch_bounds__(256) k_sumenc(const int* __restrict__ idx,
                                                const float* __restrict__ z,
                                                float* __restrict__ cs,
                                                float* __restrict__ sumenc) {
    int k = blockIdx.x;
    int wave = threadIdx.x >> 6, lane = threadIdx.x & 63;
    float acc = 0.f;
    int cnt = 0;
    int base = wave * 8192;
    for (int it = 0; it < 128; ++it) {
        int n0 = base + it * 64;
        int idv = idx[n0 + lane];
        unsigned long long m = __ballot(idv == k);
        cnt += __popcll(m);
        while (m) {
            int bit = __ffsll((unsigned long long)m) - 1;  // ascending n
            m &= m - 1;
            int n = n0 + bit;
            int b = n >> 10, hw = n & 1023;
            acc = __fadd_rn(acc, z[b * 65536 + lane * 1024 + hw]);  // element c = lane
        }
    }
    __shared__ float sacc[4][64];
    __shared__ int scnt[4];
    sacc[wave][lane] = acc;
    if (lane == 0) scnt[wave] = cnt;
    __syncthreads();
    if (wave == 0) {
        float t = __fadd_rn(__fadd_rn(sacc[0][lane], sacc[1][lane]),
                            __fadd_rn(sacc[2][lane], sacc[3][lane]));
        sumenc[k * ED + lane] = t;
        if (lane == 0) cs[k] = (float)(scnt[0] + scnt[1] + scnt[2] + scnt[3]);
    }
}

// Single block, 1024 threads: EMA cluster-size + ntot/entropy reductions +
// perplexity + codebook update. Fused.
__global__ void __launch_bounds__(1024) k_ema(const float* __restrict__ ema_cs,
                                              const float* __restrict__ ema_w,
                                              const float* __restrict__ cs,
                                              const float* __restrict__ sumenc,
                                              float* __restrict__ newemb,
                                              float* __restrict__ out) {
    int k = threadIdx.x;  // 0..1023 == NE
    float c = cs[k];
    float ncs = 0.99f * ema_cs[k] + (1.0f - 0.99f) * c;
    float p = c * (1.0f / (float)NVEC);
    float e = p * logf(p + 1e-10f);
    float rn_ = ncs, re_ = e;
#pragma unroll
    for (int o = 32; o > 0; o >>= 1) {
        rn_ += __shfl_down(rn_, o, 64);
        re_ += __shfl_down(re_, o, 64);
    }
    __shared__ float sn[16], se_[16];
    __shared__ float s_n;
    int wave = k >> 6, lane = k & 63;
    if (lane == 0) { sn[wave] = rn_; se_[wave] = re_; }
    __syncthreads();
    if (k == 0) {
        float tn = 0.f, te = 0.f;
#pragma unroll
        for (int w = 0; w < 16; ++w) { tn += sn[w]; te += se_[w]; }
        s_n = tn;
        out[O_PERP] = expf(-te);
    }
    __syncthreads();
    float nt = s_n;
    float csn = (ncs + 1e-5f) / (nt + 1024.0f * 1e-5f) * nt;
    __shared__ float s_csn[NE];
    s_csn[k] = csn;
    __syncthreads();
    for (int t = k; t < NE * ED; t += 1024) {  // coalesced
        float nw = 0.99f * ema_w[t] + (1.0f - 0.99f) * sumenc[t];
        newemb[t] = nw / s_csn[t >> 6];
    }
}

// 2048 blocks x 256 threads: z_q + straight-through + loss partials + one-hot
// rows (16/block, full 0..1023 coverage). Plain store per block; NO fences.
__global__ void __launch_bounds__(256) k_zq(const float* __restrict__ z,
                                            const int* __restrict__ idx,
                                            const float* __restrict__ newemb,
                                            float* __restrict__ out,
                                            float* __restrict__ lossp) {
    __shared__ int sbi[16];
    if (threadIdx.x < 16) sbi[threadIdx.x] = idx[blockIdx.x * 16 + threadIdx.x];
    __syncthreads();

    float local = 0.f;
#pragma unroll
    for (int i = 0; i < 4; ++i) {
        int t = blockIdx.x * 256 + threadIdx.x + i * 524288;
        int b = t >> 16, c = (t >> 10) & 63, hw = t & 1023;
        int n = (b << 10) | hw;
        float e = newemb[idx[n] * ED + c];
        float zv = z[t];
        float diff = e - zv;             // z_q - z
        out[O_ZQ + t] = zv + diff;       // straight-through: z + (z_q - z)
        local = fmaf(diff, diff, local);
    }

    // one-hot rows r0..r0+15 (row base ≡ 2 mod 4 floats; full coverage)
    int t = threadIdx.x;
    int r0 = blockIdx.x * 16;
    for (int r = 0; r < 16; ++r) {
        int rbi = sbi[r];
        float* rp = out + O_MINENC + (size_t)(r0 + r) * NE;
        if (t < 254) {
            int col = 2 + t * 4;
            float4 v;
            v.x = (col == rbi) ? 1.0f : 0.0f;
            v.y = (col + 1 == rbi) ? 1.0f : 0.0f;
            v.z = (col + 2 == rbi) ? 1.0f : 0.0f;
            v.w = (col + 3 == rbi) ? 1.0f : 0.0f;
            *(float4*)(rp + col) = v;
        } else if (t == 254) {
            float2 v;
            v.x = (0 == rbi) ? 1.0f : 0.0f;
            v.y = (1 == rbi) ? 1.0f : 0.0f;
            *(float2*)(rp) = v;
        } else {
            float4 v;
            v.x = (1018 == rbi) ? 1.0f : 0.0f;
            v.y = (1019 == rbi) ? 1.0f : 0.0f;
            v.z = (1020 == rbi) ? 1.0f : 0.0f;
            v.w = (1021 == rbi) ? 1.0f : 0.0f;
            *(float4*)(rp + 1018) = v;
            float2 w;
            w.x = (1022 == rbi) ? 1.0f : 0.0f;
            w.y = (1023 == rbi) ? 1.0f : 0.0f;
            *(float2*)(rp + 1022) = w;
        }
    }

#pragma unroll
    for (int o = 32; o > 0; o >>= 1) local += __shfl_down(local, o, 64);
    __shared__ float sp[4];
    int wave = threadIdx.x >> 6;
    if ((threadIdx.x & 63) == 0) sp[wave] = local;
    __syncthreads();
    if (threadIdx.x == 0)
        lossp[blockIdx.x] = (sp[0] + sp[1]) + (sp[2] + sp[3]);
}

// One block, 256 threads: reduce 2048 partials -> loss.
__global__ void __launch_bounds__(256) k_fin(const float* __restrict__ lossp,
                                             float* __restrict__ out) {
    float v = 0.f;
#pragma unroll
    for (int i = 0; i < 8; ++i) v += lossp[i * 256 + threadIdx.x];
#pragma unroll
    for (int o = 32; o > 0; o >>= 1) v += __shfl_down(v, o, 64);
    __shared__ float sp[4];
    int wave = threadIdx.x >> 6;
    if ((threadIdx.x & 63) == 0) sp[wave] = v;
    __syncthreads();
    if (threadIdx.x == 0)
        out[O_LOSS] = 0.25f * (((sp[0] + sp[1]) + (sp[2] + sp[3])) * (1.0f / (float)TOT));
}

extern "C" void kernel_launch(void* const* d_in, const int* in_sizes, int n_in,
                              void* d_out, int out_size, void* d_ws, size_t ws_size,
                              hipStream_t stream) {
    const float* z      = (const float*)d_in[0];
    const float* emb    = (const float*)d_in[1];
    const float* ema_cs = (const float*)d_in[2];
    const float* ema_w  = (const float*)d_in[3];
    float* out = (float*)d_out;
    float* ws  = (float*)d_ws;

    k_dist<<<512, 256, 0, stream>>>(z, emb, (int*)(ws + W_PIDX), out);
    k_sumenc<<<NE, 256, 0, stream>>>((const int*)(ws + W_PIDX), z, ws + W_CS,
                                     ws + W_SUMENC);
    k_ema<<<1, 1024, 0, stream>>>(ema_cs, ema_w, ws + W_CS, ws + W_SUMENC,
                                  ws + W_NEWEMB, out);
    k_zq<<<2048, 256, 0, stream>>>(z, (const int*)(ws + W_PIDX), ws + W_NEWEMB, out,
                                   ws + W_LOSSP);
    k_fin<<<1, 256, 0, stream>>>(ws + W_LOSSP, out);
}

// Round 17
// 293.327 us; speedup vs baseline: 1.3740x; 1.0181x over previous
//
#include <hip/hip_runtime.h>
#include <math.h>

#define NVEC 32768   // 32*32*32 vectors
#define NE   1024    // codebook entries
#define ED   64      // embedding dim
#define TOT  2097152 // NVEC*ED total z elements
#define NCHUNK 8     // code chunks inside k_dist
#define CHUNK  128   // codes per chunk
#define MT     64    // vectors per k_dist block

// d_out offsets (in floats): loss | z_q_st | perplexity | min_encodings | idx
#define O_LOSS   0
#define O_ZQ     1
#define O_PERP   2097153
#define O_MINENC 2097154
#define O_IDX    35651586

// d_ws offsets (in floats). No ws memset: every cell read has a producer.
#define W_PIDX   0        // [32768] final idx (int), written by k_dist
#define W_CS     32768    // [1024]
#define W_SUMENC 33792    // [1024*64]
#define W_NEWEMB 99328    // [1024*64]
#define W_LOSSP  164864   // [2048]

// R16 post-mortem: esq-once (+4 KB LDS) pushed k_dist to 54784 B — 171 B over
// the 3-blocks/CU threshold (160KB/3 = 54613) -> occupancy fell to 2 blocks/CU
// and k_dist regressed to 90 µs. Fix: s_b stride 132 -> 128. The +4 pad was
// the PRE-swizzle conflict fix; since R13 the quad-swizzle does the bank
// spreading (stores: banks (16j+4c4+s)%32 = every bank exactly 2x = free;
// reads: 4 broadcast-quads 8 banks apart). 32 quads x 4 = exactly 128 floats.
// New LDS 53504 B -> 3 blocks/CU restored WITH prefetch + esq-once active.
__global__ void __launch_bounds__(256, 3) k_dist(const float* __restrict__ z,
                                                 const float* __restrict__ emb,
                                                 int* __restrict__ fidx,
                                                 float* __restrict__ out) {
    __shared__ __align__(16) float s_a[64 * 64];    // [c][m] : 2*z (16 KB)
    __shared__ __align__(16) float s_b[64 * 128];   // [c][k-swizzled] (32 KB)
    __shared__ float s_esq[NE];                     // all 1024 ||e||^2 (4 KB)
    __shared__ float s_zsq[MT];

    int tid = threadIdx.x;
    int n0 = blockIdx.x * MT;
    int b = n0 >> 10, hw0 = n0 & 1023;  // MT=64 tile never crosses a b boundary
    const float* zb = z + b * 65536 + hw0;

    // Stage A once: 64c x 64m = 1024 float4, coalesced; store 2*z (exact x2)
#pragma unroll
    for (int j = 0; j < 4; ++j) {
        int f4i = j * 256 + tid;
        int c = f4i >> 4, pos = (f4i & 15) * 4;
        float4 v = *(const float4*)(zb + (c << 10) + pos);
        v.x = __fmul_rn(2.0f, v.x);
        v.y = __fmul_rn(2.0f, v.y);
        v.z = __fmul_rn(2.0f, v.z);
        v.w = __fmul_rn(2.0f, v.w);
        *(float4*)(s_a + c * 64 + pos) = v;
    }
    // All 1024 esq once (np-pairwise, 4 codes/thread); emb is L2-hot.
#pragma unroll
    for (int j = 0; j < 4; ++j) {
        int k = j * 256 + tid;
        const float* ep = emb + (size_t)k * ED;
        float r[8];
#pragma unroll
        for (int u = 0; u < 8; ++u) r[u] = __fmul_rn(ep[u], ep[u]);
#pragma unroll
        for (int i = 8; i < 64; i += 8)
#pragma unroll
            for (int u = 0; u < 8; ++u)
                r[u] = __fadd_rn(r[u], __fmul_rn(ep[i + u], ep[i + u]));
        s_esq[k] = __fadd_rn(
            __fadd_rn(__fadd_rn(r[0], r[1]), __fadd_rn(r[2], r[3])),
            __fadd_rn(__fadd_rn(r[4], r[5]), __fadd_rn(r[6], r[7])));
    }
    __syncthreads();

    // zsq once (threads 0..63): np-pairwise over z; from (2z): exact x0.25.
    if (tid < MT) {
        float r[8];
#pragma unroll
        for (int j = 0; j < 8; ++j) {
            float v = s_a[j * 64 + tid];
            r[j] = __fmul_rn(v, v);
        }
#pragma unroll
        for (int i = 8; i < 64; i += 8)
#pragma unroll
            for (int j = 0; j < 8; ++j) {
                float v = s_a[(i + j) * 64 + tid];
                r[j] = __fadd_rn(r[j], __fmul_rn(v, v));
            }
        s_zsq[tid] = __fmul_rn(0.25f, __fadd_rn(
            __fadd_rn(__fadd_rn(r[0], r[1]), __fadd_rn(r[2], r[3])),
            __fadd_rn(__fadd_rn(r[4], r[5]), __fadd_rn(r[6], r[7]))));
    }
    __syncthreads();

    int mi = tid & 15, ki = tid >> 4;
    int mbase = mi * 4, kbase = ki * 8;
    float zs[4];
#pragma unroll
    for (int mu = 0; mu < 4; ++mu) zs[mu] = s_zsq[mbase + mu];

    float bd[4];
    int bix[4];
#pragma unroll
    for (int mu = 0; mu < 4; ++mu) { bd[mu] = 3.4e38f; bix[mu] = kbase; }

    // This thread's staging slice: 8 float4s per chunk (f4i = j*256+tid).
    int s_kl[8], s_c4[8];
#pragma unroll
    for (int j = 0; j < 8; ++j) {
        int f4i = j * 256 + tid;
        s_kl[j] = f4i >> 4;
        s_c4[j] = f4i & 15;
    }

    // Prefetch chunk 0.
    float4 pf[8];
#pragma unroll
    for (int j = 0; j < 8; ++j)
        pf[j] = *(const float4*)(emb + (size_t)s_kl[j] * ED + s_c4[j] * 4);

    for (int q = 0; q < NCHUNK; ++q) {
        __syncthreads();  // previous chunk's readers of s_b are done
        // Store prefetched B transposed+swizzled: phys quad (k4+c4)&31.
#pragma unroll
        for (int j = 0; j < 8; ++j) {
            int kl = s_kl[j], c4 = s_c4[j];
            int base = (((kl >> 2) + c4) & 31) * 4 + (kl & 3);
            s_b[(c4 * 4 + 0) * 128 + base] = pf[j].x;
            s_b[(c4 * 4 + 1) * 128 + base] = pf[j].y;
            s_b[(c4 * 4 + 2) * 128 + base] = pf[j].z;
            s_b[(c4 * 4 + 3) * 128 + base] = pf[j].w;
        }
        // Issue next chunk's loads now; latency overlaps this chunk's compute.
        if (q + 1 < NCHUNK) {
            const float* nb = emb + (size_t)(q + 1) * CHUNK * ED;
#pragma unroll
            for (int j = 0; j < 8; ++j)
                pf[j] = *(const float4*)(nb + (size_t)s_kl[j] * ED + s_c4[j] * 4);
        }
        __syncthreads();  // staging visible

        int k0 = q * CHUNK;
        float acc[4][8];
#pragma unroll
        for (int mu = 0; mu < 4; ++mu)
#pragma unroll
            for (int ku = 0; ku < 8; ++ku) acc[mu][ku] = 0.f;

#pragma unroll 4
        for (int c = 0; c < 64; ++c) {
            int c4 = c >> 2;
            float4 av = *(const float4*)(s_a + c * 64 + mbase);
            float4 b0 = *(const float4*)(s_b + c * 128 + ((2 * ki + c4) & 31) * 4);
            float4 b1 = *(const float4*)(s_b + c * 128 + ((2 * ki + 1 + c4) & 31) * 4);
#pragma unroll
            for (int mu = 0; mu < 4; ++mu) {
                float a = (&av.x)[mu];
                acc[mu][0] = __fmaf_rn(a, b0.x, acc[mu][0]);
                acc[mu][1] = __fmaf_rn(a, b0.y, acc[mu][1]);
                acc[mu][2] = __fmaf_rn(a, b0.z, acc[mu][2]);
                acc[mu][3] = __fmaf_rn(a, b0.w, acc[mu][3]);
                acc[mu][4] = __fmaf_rn(a, b1.x, acc[mu][4]);
                acc[mu][5] = __fmaf_rn(a, b1.y, acc[mu][5]);
                acc[mu][6] = __fmaf_rn(a, b1.z, acc[mu][6]);
                acc[mu][7] = __fmaf_rn(a, b1.w, acc[mu][7]);
            }
        }

        // d = fl(fl(zsq+esq) - dot2); running per-thread argmin (k ascending)
#pragma unroll
        for (int mu = 0; mu < 4; ++mu)
#pragma unroll
            for (int ku = 0; ku < 8; ++ku) {
                float d = __fsub_rn(__fadd_rn(zs[mu], s_esq[k0 + kbase + ku]),
                                    acc[mu][ku]);
                if (d < bd[mu]) { bd[mu] = d; bix[mu] = k0 + kbase + ku; }
            }
    }

    // Merge 16 ki candidates per m with lexicographic (d, i) min ==
    // np.argmin lowest-index-among-minima. Reuse s_b as scratch.
    __syncthreads();
    float* red_d = s_b;               // [16][64]
    int* red_i = (int*)(s_b + 1024);  // [16][64]
#pragma unroll
    for (int mu = 0; mu < 4; ++mu) {
        red_d[ki * 64 + mbase + mu] = bd[mu];
        red_i[ki * 64 + mbase + mu] = bix[mu];
    }
    __syncthreads();
    if (tid < MT) {
        float best = red_d[tid];
        int bi = red_i[tid];
#pragma unroll
        for (int q = 1; q < 16; ++q) {
            float d = red_d[q * 64 + tid];
            int i = red_i[q * 64 + tid];
            if (d < best || (d == best && i < bi)) { best = d; bi = i; }
        }
        fidx[n0 + tid] = bi;
        out[O_IDX + n0 + tid] = (float)bi;
    }
}

// Gather-based segment sum: one block per code k, 4 waves. Ballot-scan idx;
// members accumulated lane=element; popcount -> cs. Deterministic. No atomics.
__global__ void __launch_bounds__(256) k_sumenc(const int* __restrict__ idx,
                                                const float* __restrict__ z,
                                                float* __restrict__ cs,
                                                float* __restrict__ sumenc) {
    int k = blockIdx.x;
    int wave = threadIdx.x >> 6, lane = threadIdx.x & 63;
    float acc = 0.f;
    int cnt = 0;
    int base = wave * 8192;
    for (int it = 0; it < 128; ++it) {
        int n0 = base + it * 64;
        int idv = idx[n0 + lane];
        unsigned long long m = __ballot(idv == k);
        cnt += __popcll(m);
        while (m) {
            int bit = __ffsll((unsigned long long)m) - 1;  // ascending n
            m &= m - 1;
            int n = n0 + bit;
            int b = n >> 10, hw = n & 1023;
            acc = __fadd_rn(acc, z[b * 65536 + lane * 1024 + hw]);  // element c = lane
        }
    }
    __shared__ float sacc[4][64];
    __shared__ int scnt[4];
    sacc[wave][lane] = acc;
    if (lane == 0) scnt[wave] = cnt;
    __syncthreads();
    if (wave == 0) {
        float t = __fadd_rn(__fadd_rn(sacc[0][lane], sacc[1][lane]),
                            __fadd_rn(sacc[2][lane], sacc[3][lane]));
        sumenc[k * ED + lane] = t;
        if (lane == 0) cs[k] = (float)(scnt[0] + scnt[1] + scnt[2] + scnt[3]);
    }
}

// Single block, 1024 threads: EMA cluster-size + ntot/entropy reductions +
// perplexity + codebook update. Fused.
__global__ void __launch_bounds__(1024) k_ema(const float* __restrict__ ema_cs,
                                              const float* __restrict__ ema_w,
                                              const float* __restrict__ cs,
                                              const float* __restrict__ sumenc,
                                              float* __restrict__ newemb,
                                              float* __restrict__ out) {
    int k = threadIdx.x;  // 0..1023 == NE
    float c = cs[k];
    float ncs = 0.99f * ema_cs[k] + (1.0f - 0.99f) * c;
    float p = c * (1.0f / (float)NVEC);
    float e = p * logf(p + 1e-10f);
    float rn_ = ncs, re_ = e;
#pragma unroll
    for (int o = 32; o > 0; o >>= 1) {
        rn_ += __shfl_down(rn_, o, 64);
        re_ += __shfl_down(re_, o, 64);
    }
    __shared__ float sn[16], se_[16];
    __shared__ float s_n;
    int wave = k >> 6, lane = k & 63;
    if (lane == 0) { sn[wave] = rn_; se_[wave] = re_; }
    __syncthreads();
    if (k == 0) {
        float tn = 0.f, te = 0.f;
#pragma unroll
        for (int w = 0; w < 16; ++w) { tn += sn[w]; te += se_[w]; }
        s_n = tn;
        out[O_PERP] = expf(-te);
    }
    __syncthreads();
    float nt = s_n;
    float csn = (ncs + 1e-5f) / (nt + 1024.0f * 1e-5f) * nt;
    __shared__ float s_csn[NE];
    s_csn[k] = csn;
    __syncthreads();
    for (int t = k; t < NE * ED; t += 1024) {  // coalesced
        float nw = 0.99f * ema_w[t] + (1.0f - 0.99f) * sumenc[t];
        newemb[t] = nw / s_csn[t >> 6];
    }
}

// 2048 blocks x 256 threads: z_q + straight-through + loss partials + one-hot
// rows (16/block, full 0..1023 coverage). Plain store per block; NO fences.
__global__ void __launch_bounds__(256) k_zq(const float* __restrict__ z,
                                            const int* __restrict__ idx,
                                            const float* __restrict__ newemb,
                                            float* __restrict__ out,
                                            float* __restrict__ lossp) {
    __shared__ int sbi[16];
    if (threadIdx.x < 16) sbi[threadIdx.x] = idx[blockIdx.x * 16 + threadIdx.x];
    __syncthreads();

    float local = 0.f;
#pragma unroll
    for (int i = 0; i < 4; ++i) {
        int t = blockIdx.x * 256 + threadIdx.x + i * 524288;
        int b = t >> 16, c = (t >> 10) & 63, hw = t & 1023;
        int n = (b << 10) | hw;
        float e = newemb[idx[n] * ED + c];
        float zv = z[t];
        float diff = e - zv;             // z_q - z
        out[O_ZQ + t] = zv + diff;       // straight-through: z + (z_q - z)
        local = fmaf(diff, diff, local);
    }

    // one-hot rows r0..r0+15 (row base ≡ 2 mod 4 floats; full coverage)
    int t = threadIdx.x;
    int r0 = blockIdx.x * 16;
    for (int r = 0; r < 16; ++r) {
        int rbi = sbi[r];
        float* rp = out + O_MINENC + (size_t)(r0 + r) * NE;
        if (t < 254) {
            int col = 2 + t * 4;
            float4 v;
            v.x = (col == rbi) ? 1.0f : 0.0f;
            v.y = (col + 1 == rbi) ? 1.0f : 0.0f;
            v.z = (col + 2 == rbi) ? 1.0f : 0.0f;
            v.w = (col + 3 == rbi) ? 1.0f : 0.0f;
            *(float4*)(rp + col) = v;
        } else if (t == 254) {
            float2 v;
            v.x = (0 == rbi) ? 1.0f : 0.0f;
            v.y = (1 == rbi) ? 1.0f : 0.0f;
            *(float2*)(rp) = v;
        } else {
            float4 v;
            v.x = (1018 == rbi) ? 1.0f : 0.0f;
            v.y = (1019 == rbi) ? 1.0f : 0.0f;
            v.z = (1020 == rbi) ? 1.0f : 0.0f;
            v.w = (1021 == rbi) ? 1.0f : 0.0f;
            *(float4*)(rp + 1018) = v;
            float2 w;
            w.x = (1022 == rbi) ? 1.0f : 0.0f;
            w.y = (1023 == rbi) ? 1.0f : 0.0f;
            *(float2*)(rp + 1022) = w;
        }
    }

#pragma unroll
    for (int o = 32; o > 0; o >>= 1) local += __shfl_down(local, o, 64);
    __shared__ float sp[4];
    int wave = threadIdx.x >> 6;
    if ((threadIdx.x & 63) == 0) sp[wave] = local;
    __syncthreads();
    if (threadIdx.x == 0)
        lossp[blockIdx.x] = (sp[0] + sp[1]) + (sp[2] + sp[3]);
}

// One block, 256 threads: reduce 2048 partials -> loss.
__global__ void __launch_bounds__(256) k_fin(const float* __restrict__ lossp,
                                             float* __restrict__ out) {
    float v = 0.f;
#pragma unroll
    for (int i = 0; i < 8; ++i) v += lossp[i * 256 + threadIdx.x];
#pragma unroll
    for (int o = 32; o > 0; o >>= 1) v += __shfl_down(v, o, 64);
    __shared__ float sp[4];
    int wave = threadIdx.x >> 6;
    if ((threadIdx.x & 63) == 0) sp[wave] = v;
    __syncthreads();
    if (threadIdx.x == 0)
        out[O_LOSS] = 0.25f * (((sp[0] + sp[1]) + (sp[2] + sp[3])) * (1.0f / (float)TOT));
}

extern "C" void kernel_launch(void* const* d_in, const int* in_sizes, int n_in,
                              void* d_out, int out_size, void* d_ws, size_t ws_size,
                              hipStream_t stream) {
    const float* z      = (const float*)d_in[0];
    const float* emb    = (const float*)d_in[1];
    const float* ema_cs = (const float*)d_in[2];
    const float* ema_w  = (const float*)d_in[3];
    float* out = (float*)d_out;
    float* ws  = (float*)d_ws;

    k_dist<<<512, 256, 0, stream>>>(z, emb, (int*)(ws + W_PIDX), out);
    k_sumenc<<<NE, 256, 0, stream>>>((const int*)(ws + W_PIDX), z, ws + W_CS,
                                     ws + W_SUMENC);
    k_ema<<<1, 1024, 0, stream>>>(ema_cs, ema_w, ws + W_CS, ws + W_SUMENC,
                                  ws + W_NEWEMB, out);
    k_zq<<<2048, 256, 0, stream>>>(z, (const int*)(ws + W_PIDX), ws + W_NEWEMB, out,
                                   ws + W_LOSSP);
    k_fin<<<1, 256, 0, stream>>>(ws + W_LOSSP, out);
}

// Round 18
// 291.577 us; speedup vs baseline: 1.3823x; 1.0060x over previous
//
#include <hip/hip_runtime.h>
#include <math.h>

#define NVEC 32768   // 32*32*32 vectors
#define NE   1024    // codebook entries
#define ED   64      // embedding dim
#define TOT  2097152 // NVEC*ED total z elements
#define NCHUNK 8     // code chunks inside k_dist
#define CHUNK  128   // codes per chunk
#define MT     64    // vectors per k_dist block

// d_out offsets (in floats): loss | z_q_st | perplexity | min_encodings | idx
#define O_LOSS   0
#define O_ZQ     1
#define O_PERP   2097153
#define O_MINENC 2097154
#define O_IDX    35651586

// d_ws offsets (in floats). No ws memset: every cell read has a producer.
#define W_PIDX   0        // [32768] final idx (int), written by k_dist
#define W_CS     32768    // [1024]
#define W_SUMENC 33792    // [1024*64]
#define W_NEWEMB 99328    // [1024*64]
#define W_LOSSP  164864   // [2048]

// R17 post-mortem: occupancy was GRID-limited, not LDS-limited — 512 blocks
// on 256 CUs = 2 blocks/CU = 2 waves/SIMD regardless of LDS (VALUBusy 47%,
// 87 µs vs 27 µs FMA floor: too few waves to hide ds_read latency + chunk
// barriers). Fix: 512-thread blocks (8 waves) — same grid, same tile, same
// 53.5 KB LDS, but 16 waves/CU = 4 waves/SIMD. Each thread: 4m x 4k = 16 acc
// (ki 0..31), ONE ds_read_b128 for b per c-step. Same ascending-c FMA chain
// per (n,k) -> bit-identical; merge = 32 ki-groups ascending, lexicographic
// (d,i) = np.argmin first-index semantics.
__global__ void __launch_bounds__(512, 4) k_dist(const float* __restrict__ z,
                                                 const float* __restrict__ emb,
                                                 int* __restrict__ fidx,
                                                 float* __restrict__ out) {
    __shared__ __align__(16) float s_a[64 * 64];    // [c][m] : 2*z (16 KB)
    __shared__ __align__(16) float s_b[64 * 128];   // [c][k-swizzled] (32 KB)
    __shared__ float s_esq[NE];                     // all 1024 ||e||^2 (4 KB)
    __shared__ float s_zsq[MT];

    int tid = threadIdx.x;  // 0..511
    int n0 = blockIdx.x * MT;
    int b = n0 >> 10, hw0 = n0 & 1023;  // MT=64 tile never crosses a b boundary
    const float* zb = z + b * 65536 + hw0;

    // Stage A once: 1024 float4 / 512 threads = 2 each; store 2*z (exact x2)
#pragma unroll
    for (int j = 0; j < 2; ++j) {
        int f4i = j * 512 + tid;
        int c = f4i >> 4, pos = (f4i & 15) * 4;
        float4 v = *(const float4*)(zb + (c << 10) + pos);
        v.x = __fmul_rn(2.0f, v.x);
        v.y = __fmul_rn(2.0f, v.y);
        v.z = __fmul_rn(2.0f, v.z);
        v.w = __fmul_rn(2.0f, v.w);
        *(float4*)(s_a + c * 64 + pos) = v;
    }
    // All 1024 esq once (np-pairwise, 2 codes/thread); emb is L2-hot.
#pragma unroll
    for (int j = 0; j < 2; ++j) {
        int k = j * 512 + tid;
        const float* ep = emb + (size_t)k * ED;
        float r[8];
#pragma unroll
        for (int u = 0; u < 8; ++u) r[u] = __fmul_rn(ep[u], ep[u]);
#pragma unroll
        for (int i = 8; i < 64; i += 8)
#pragma unroll
            for (int u = 0; u < 8; ++u)
                r[u] = __fadd_rn(r[u], __fmul_rn(ep[i + u], ep[i + u]));
        s_esq[k] = __fadd_rn(
            __fadd_rn(__fadd_rn(r[0], r[1]), __fadd_rn(r[2], r[3])),
            __fadd_rn(__fadd_rn(r[4], r[5]), __fadd_rn(r[6], r[7])));
    }
    __syncthreads();

    // zsq once (threads 0..63): np-pairwise over z; from (2z): exact x0.25.
    if (tid < MT) {
        float r[8];
#pragma unroll
        for (int j = 0; j < 8; ++j) {
            float v = s_a[j * 64 + tid];
            r[j] = __fmul_rn(v, v);
        }
#pragma unroll
        for (int i = 8; i < 64; i += 8)
#pragma unroll
            for (int j = 0; j < 8; ++j) {
                float v = s_a[(i + j) * 64 + tid];
                r[j] = __fadd_rn(r[j], __fmul_rn(v, v));
            }
        s_zsq[tid] = __fmul_rn(0.25f, __fadd_rn(
            __fadd_rn(__fadd_rn(r[0], r[1]), __fadd_rn(r[2], r[3])),
            __fadd_rn(__fadd_rn(r[4], r[5]), __fadd_rn(r[6], r[7]))));
    }
    __syncthreads();

    int mi = tid & 15, ki = tid >> 4;   // mi 0..15, ki 0..31
    int mbase = mi * 4, kbase = ki * 4;
    float zs[4];
#pragma unroll
    for (int mu = 0; mu < 4; ++mu) zs[mu] = s_zsq[mbase + mu];

    float bd[4];
    int bix[4];
#pragma unroll
    for (int mu = 0; mu < 4; ++mu) { bd[mu] = 3.4e38f; bix[mu] = kbase; }

    // This thread's staging slice: 4 float4s per chunk (f4i = j*512+tid).
    int s_kl[4], s_c4[4];
#pragma unroll
    for (int j = 0; j < 4; ++j) {
        int f4i = j * 512 + tid;
        s_kl[j] = f4i >> 4;
        s_c4[j] = f4i & 15;
    }

    // Prefetch chunk 0.
    float4 pf[4];
#pragma unroll
    for (int j = 0; j < 4; ++j)
        pf[j] = *(const float4*)(emb + (size_t)s_kl[j] * ED + s_c4[j] * 4);

    for (int q = 0; q < NCHUNK; ++q) {
        __syncthreads();  // previous chunk's readers of s_b are done
        // Store prefetched B transposed+swizzled: phys quad (k4+c4)&31.
#pragma unroll
        for (int j = 0; j < 4; ++j) {
            int kl = s_kl[j], c4 = s_c4[j];
            int base = (((kl >> 2) + c4) & 31) * 4 + (kl & 3);
            s_b[(c4 * 4 + 0) * 128 + base] = pf[j].x;
            s_b[(c4 * 4 + 1) * 128 + base] = pf[j].y;
            s_b[(c4 * 4 + 2) * 128 + base] = pf[j].z;
            s_b[(c4 * 4 + 3) * 128 + base] = pf[j].w;
        }
        // Issue next chunk's loads now; latency overlaps this chunk's compute.
        if (q + 1 < NCHUNK) {
            const float* nb = emb + (size_t)(q + 1) * CHUNK * ED;
#pragma unroll
            for (int j = 0; j < 4; ++j)
                pf[j] = *(const float4*)(nb + (size_t)s_kl[j] * ED + s_c4[j] * 4);
        }
        __syncthreads();  // staging visible

        int k0 = q * CHUNK;
        float acc[4][4];
#pragma unroll
        for (int mu = 0; mu < 4; ++mu)
#pragma unroll
            for (int ku = 0; ku < 4; ++ku) acc[mu][ku] = 0.f;

#pragma unroll 4
        for (int c = 0; c < 64; ++c) {
            int c4 = c >> 2;
            float4 av = *(const float4*)(s_a + c * 64 + mbase);
            float4 b0 = *(const float4*)(s_b + c * 128 + ((ki + c4) & 31) * 4);
#pragma unroll
            for (int mu = 0; mu < 4; ++mu) {
                float a = (&av.x)[mu];
                acc[mu][0] = __fmaf_rn(a, b0.x, acc[mu][0]);
                acc[mu][1] = __fmaf_rn(a, b0.y, acc[mu][1]);
                acc[mu][2] = __fmaf_rn(a, b0.z, acc[mu][2]);
                acc[mu][3] = __fmaf_rn(a, b0.w, acc[mu][3]);
            }
        }

        // d = fl(fl(zsq+esq) - dot2); running per-thread argmin (k ascending)
#pragma unroll
        for (int mu = 0; mu < 4; ++mu)
#pragma unroll
            for (int ku = 0; ku < 4; ++ku) {
                float d = __fsub_rn(__fadd_rn(zs[mu], s_esq[k0 + kbase + ku]),
                                    acc[mu][ku]);
                if (d < bd[mu]) { bd[mu] = d; bix[mu] = k0 + kbase + ku; }
            }
    }

    // Merge 32 ki candidates per m with lexicographic (d, i) min ==
    // np.argmin lowest-index-among-minima. Reuse s_b as scratch.
    __syncthreads();
    float* red_d = s_b;               // [32][64]
    int* red_i = (int*)(s_b + 2048);  // [32][64]
#pragma unroll
    for (int mu = 0; mu < 4; ++mu) {
        red_d[ki * 64 + mbase + mu] = bd[mu];
        red_i[ki * 64 + mbase + mu] = bix[mu];
    }
    __syncthreads();
    if (tid < MT) {
        float best = red_d[tid];
        int bi = red_i[tid];
#pragma unroll
        for (int q = 1; q < 32; ++q) {
            float d = red_d[q * 64 + tid];
            int i = red_i[q * 64 + tid];
            if (d < best || (d == best && i < bi)) { best = d; bi = i; }
        }
        fidx[n0 + tid] = bi;
        out[O_IDX + n0 + tid] = (float)bi;
    }
}

// Gather-based segment sum: one block per code k, 4 waves. Ballot-scan idx;
// members accumulated lane=element; popcount -> cs. Deterministic. No atomics.
__global__ void __launch_bounds__(256) k_sumenc(const int* __restrict__ idx,
                                                const float* __restrict__ z,
                                                float* __restrict__ cs,
                                                float* __restrict__ sumenc) {
    int k = blockIdx.x;
    int wave = threadIdx.x >> 6, lane = threadIdx.x & 63;
    float acc = 0.f;
    int cnt = 0;
    int base = wave * 8192;
    for (int it = 0; it < 128; ++it) {
        int n0 = base + it * 64;
        int idv = idx[n0 + lane];
        unsigned long long m = __ballot(idv == k);
        cnt += __popcll(m);
        while (m) {
            int bit = __ffsll((unsigned long long)m) - 1;  // ascending n
            m &= m - 1;
            int n = n0 + bit;
            int b = n >> 10, hw = n & 1023;
            acc = __fadd_rn(acc, z[b * 65536 + lane * 1024 + hw]);  // element c = lane
        }
    }
    __shared__ float sacc[4][64];
    __shared__ int scnt[4];
    sacc[wave][lane] = acc;
    if (lane == 0) scnt[wave] = cnt;
    __syncthreads();
    if (wave == 0) {
        float t = __fadd_rn(__fadd_rn(sacc[0][lane], sacc[1][lane]),
                            __fadd_rn(sacc[2][lane], sacc[3][lane]));
        sumenc[k * ED + lane] = t;
        if (lane == 0) cs[k] = (float)(scnt[0] + scnt[1] + scnt[2] + scnt[3]);
    }
}

// Single block, 1024 threads: EMA cluster-size + ntot/entropy reductions +
// perplexity + codebook update. Fused.
__global__ void __launch_bounds__(1024) k_ema(const float* __restrict__ ema_cs,
                                              const float* __restrict__ ema_w,
                                              const float* __restrict__ cs,
                                              const float* __restrict__ sumenc,
                                              float* __restrict__ newemb,
                                              float* __restrict__ out) {
    int k = threadIdx.x;  // 0..1023 == NE
    float c = cs[k];
    float ncs = 0.99f * ema_cs[k] + (1.0f - 0.99f) * c;
    float p = c * (1.0f / (float)NVEC);
    float e = p * logf(p + 1e-10f);
    float rn_ = ncs, re_ = e;
#pragma unroll
    for (int o = 32; o > 0; o >>= 1) {
        rn_ += __shfl_down(rn_, o, 64);
        re_ += __shfl_down(re_, o, 64);
    }
    __shared__ float sn[16], se_[16];
    __shared__ float s_n;
    int wave = k >> 6, lane = k & 63;
    if (lane == 0) { sn[wave] = rn_; se_[wave] = re_; }
    __syncthreads();
    if (k == 0) {
        float tn = 0.f, te = 0.f;
#pragma unroll
        for (int w = 0; w < 16; ++w) { tn += sn[w]; te += se_[w]; }
        s_n = tn;
        out[O_PERP] = expf(-te);
    }
    __syncthreads();
    float nt = s_n;
    float csn = (ncs + 1e-5f) / (nt + 1024.0f * 1e-5f) * nt;
    __shared__ float s_csn[NE];
    s_csn[k] = csn;
    __syncthreads();
    for (int t = k; t < NE * ED; t += 1024) {  // coalesced
        float nw = 0.99f * ema_w[t] + (1.0f - 0.99f) * sumenc[t];
        newemb[t] = nw / s_csn[t >> 6];
    }
}

// 2048 blocks x 256 threads: z_q + straight-through + loss partials + one-hot
// rows (16/block, full 0..1023 coverage). Plain store per block; NO fences.
__global__ void __launch_bounds__(256) k_zq(const float* __restrict__ z,
                                            const int* __restrict__ idx,
                                            const float* __restrict__ newemb,
                                            float* __restrict__ out,
                                            float* __restrict__ lossp) {
    __shared__ int sbi[16];
    if (threadIdx.x < 16) sbi[threadIdx.x] = idx[blockIdx.x * 16 + threadIdx.x];
    __syncthreads();

    float local = 0.f;
#pragma unroll
    for (int i = 0; i < 4; ++i) {
        int t = blockIdx.x * 256 + threadIdx.x + i * 524288;
        int b = t >> 16, c = (t >> 10) & 63, hw = t & 1023;
        int n = (b << 10) | hw;
        float e = newemb[idx[n] * ED + c];
        float zv = z[t];
        float diff = e - zv;             // z_q - z
        out[O_ZQ + t] = zv + diff;       // straight-through: z + (z_q - z)
        local = fmaf(diff, diff, local);
    }

    // one-hot rows r0..r0+15 (row base ≡ 2 mod 4 floats; full coverage)
    int t = threadIdx.x;
    int r0 = blockIdx.x * 16;
    for (int r = 0; r < 16; ++r) {
        int rbi = sbi[r];
        float* rp = out + O_MINENC + (size_t)(r0 + r) * NE;
        if (t < 254) {
            int col = 2 + t * 4;
            float4 v;
            v.x = (col == rbi) ? 1.0f : 0.0f;
            v.y = (col + 1 == rbi) ? 1.0f : 0.0f;
            v.z = (col + 2 == rbi) ? 1.0f : 0.0f;
            v.w = (col + 3 == rbi) ? 1.0f : 0.0f;
            *(float4*)(rp + col) = v;
        } else if (t == 254) {
            float2 v;
            v.x = (0 == rbi) ? 1.0f : 0.0f;
            v.y = (1 == rbi) ? 1.0f : 0.0f;
            *(float2*)(rp) = v;
        } else {
            float4 v;
            v.x = (1018 == rbi) ? 1.0f : 0.0f;
            v.y = (1019 == rbi) ? 1.0f : 0.0f;
            v.z = (1020 == rbi) ? 1.0f : 0.0f;
            v.w = (1021 == rbi) ? 1.0f : 0.0f;
            *(float4*)(rp + 1018) = v;
            float2 w;
            w.x = (1022 == rbi) ? 1.0f : 0.0f;
            w.y = (1023 == rbi) ? 1.0f : 0.0f;
            *(float2*)(rp + 1022) = w;
        }
    }

#pragma unroll
    for (int o = 32; o > 0; o >>= 1) local += __shfl_down(local, o, 64);
    __shared__ float sp[4];
    int wave = threadIdx.x >> 6;
    if ((threadIdx.x & 63) == 0) sp[wave] = local;
    __syncthreads();
    if (threadIdx.x == 0)
        lossp[blockIdx.x] = (sp[0] + sp[1]) + (sp[2] + sp[3]);
}

// One block, 256 threads: reduce 2048 partials -> loss.
__global__ void __launch_bounds__(256) k_fin(const float* __restrict__ lossp,
                                             float* __restrict__ out) {
    float v = 0.f;
#pragma unroll
    for (int i = 0; i < 8; ++i) v += lossp[i * 256 + threadIdx.x];
#pragma unroll
    for (int o = 32; o > 0; o >>= 1) v += __shfl_down(v, o, 64);
    __shared__ float sp[4];
    int wave = threadIdx.x >> 6;
    if ((threadIdx.x & 63) == 0) sp[wave] = v;
    __syncthreads();
    if (threadIdx.x == 0)
        out[O_LOSS] = 0.25f * (((sp[0] + sp[1]) + (sp[2] + sp[3])) * (1.0f / (float)TOT));
}

extern "C" void kernel_launch(void* const* d_in, const int* in_sizes, int n_in,
                              void* d_out, int out_size, void* d_ws, size_t ws_size,
                              hipStream_t stream) {
    const float* z      = (const float*)d_in[0];
    const float* emb    = (const float*)d_in[1];
    const float* ema_cs = (const float*)d_in[2];
    const float* ema_w  = (const float*)d_in[3];
    float* out = (float*)d_out;
    float* ws  = (float*)d_ws;

    k_dist<<<512, 512, 0, stream>>>(z, emb, (int*)(ws + W_PIDX), out);
    k_sumenc<<<NE, 256, 0, stream>>>((const int*)(ws + W_PIDX), z, ws + W_CS,
                                     ws + W_SUMENC);
    k_ema<<<1, 1024, 0, stream>>>(ema_cs, ema_w, ws + W_CS, ws + W_SUMENC,
                                  ws + W_NEWEMB, out);
    k_zq<<<2048, 256, 0, stream>>>(z, (const int*)(ws + W_PIDX), ws + W_NEWEMB, out,
                                   ws + W_LOSSP);
    k_fin<<<1, 256, 0, stream>>>(ws + W_LOSSP, out);
}

// Round 19
// 286.134 us; speedup vs baseline: 1.4086x; 1.0190x over previous
//
#include <hip/hip_runtime.h>
#include <math.h>

#define NVEC 32768   // 32*32*32 vectors
#define NE   1024    // codebook entries
#define ED   64      // embedding dim
#define TOT  2097152 // NVEC*ED total z elements
#define NCHUNK 8     // code chunks inside k_dist
#define CHUNK  128   // codes per chunk
#define MT     64    // vectors per k_dist block

// d_out offsets (in floats): loss | z_q_st | perplexity | min_encodings | idx
#define O_LOSS   0
#define O_ZQ     1
#define O_PERP   2097153
#define O_MINENC 2097154
#define O_IDX    35651586

// d_ws offsets (in floats). No ws memset: every cell read has a producer.
#define W_PIDX   0        // [32768] final idx (int), written by k_dist
#define W_CS     32768    // [1024]
#define W_SUMENC 33792    // [1024*64]
#define W_NEWEMB 99328    // [1024*64]
#define W_LOSSP  164864   // [2048]

// R18 post-mortem: the trajectory's best total (285.8 µs, R14 bench) used
// THIS k_dist: 256 thr, stride-132 swizzle, per-chunk esq, no prefetch,
// LDS 50944 -> 3 blocks/CU = 12 waves/CU. All successors (esq-once+prefetch
// 54784B -> 2 blocks/CU: 298.6; stride-128: 293.3; 512-thr: 291.6) benched
// worse or noise-equal (noise band ±7-13 µs, R14 vs R16 identical code).
// 12 waves/CU beats the instruction savings. Evidence-first revert.
__global__ void __launch_bounds__(256, 3) k_dist(const float* __restrict__ z,
                                                 const float* __restrict__ emb,
                                                 int* __restrict__ fidx,
                                                 float* __restrict__ out) {
    __shared__ __align__(16) float s_a[64 * 64];    // [c][m] : 2*z (16 KB)
    __shared__ __align__(16) float s_b[64 * 132];   // [c][k-swizzled] (33 KB)
    __shared__ float s_esq[CHUNK];
    __shared__ float s_zsq[MT];

    int tid = threadIdx.x;
    int n0 = blockIdx.x * MT;
    int b = n0 >> 10, hw0 = n0 & 1023;  // MT=64 tile never crosses a b boundary
    const float* zb = z + b * 65536 + hw0;

    // Stage A once: 64c x 64m = 1024 float4, coalesced; store 2*z (exact x2)
#pragma unroll
    for (int j = 0; j < 4; ++j) {
        int f4i = j * 256 + tid;
        int c = f4i >> 4, pos = (f4i & 15) * 4;
        float4 v = *(const float4*)(zb + (c << 10) + pos);
        v.x = __fmul_rn(2.0f, v.x);
        v.y = __fmul_rn(2.0f, v.y);
        v.z = __fmul_rn(2.0f, v.z);
        v.w = __fmul_rn(2.0f, v.w);
        *(float4*)(s_a + c * 64 + pos) = v;
    }
    __syncthreads();

    // zsq once (threads 0..63): np-pairwise over z; from (2z): exact x0.25.
    if (tid < MT) {
        float r[8];
#pragma unroll
        for (int j = 0; j < 8; ++j) {
            float v = s_a[j * 64 + tid];
            r[j] = __fmul_rn(v, v);
        }
#pragma unroll
        for (int i = 8; i < 64; i += 8)
#pragma unroll
            for (int j = 0; j < 8; ++j) {
                float v = s_a[(i + j) * 64 + tid];
                r[j] = __fadd_rn(r[j], __fmul_rn(v, v));
            }
        s_zsq[tid] = __fmul_rn(0.25f, __fadd_rn(
            __fadd_rn(__fadd_rn(r[0], r[1]), __fadd_rn(r[2], r[3])),
            __fadd_rn(__fadd_rn(r[4], r[5]), __fadd_rn(r[6], r[7]))));
    }
    __syncthreads();

    int mi = tid & 15, ki = tid >> 4;
    int mbase = mi * 4, kbase = ki * 8;
    float zs[4];
#pragma unroll
    for (int mu = 0; mu < 4; ++mu) zs[mu] = s_zsq[mbase + mu];

    float bd[4];
    int bix[4];
#pragma unroll
    for (int mu = 0; mu < 4; ++mu) { bd[mu] = 3.4e38f; bix[mu] = kbase; }

    for (int q = 0; q < NCHUNK; ++q) {
        int k0 = q * CHUNK;
        __syncthreads();  // previous chunk's readers of s_b/s_esq are done
        // Stage B transposed+swizzled: phys quad (k4+c4)&31. Per store
        // instruction k4 is wave-uniform, c4 spans 0..15 -> 32 banks, 2-way.
#pragma unroll
        for (int j = 0; j < 8; ++j) {
            int f4i = j * 256 + tid;
            int kl = f4i >> 4, c4 = f4i & 15;
            float4 v = *(const float4*)(emb + (size_t)(k0 + kl) * ED + c4 * 4);
            int base = ((( kl >> 2) + c4) & 31) * 4 + (kl & 3);
            s_b[(c4 * 4 + 0) * 132 + base] = v.x;
            s_b[(c4 * 4 + 1) * 132 + base] = v.y;
            s_b[(c4 * 4 + 2) * 132 + base] = v.z;
            s_b[(c4 * 4 + 3) * 132 + base] = v.w;
        }
        // esq for this chunk from GLOBAL (np-pairwise, threads 0..127)
        if (tid < CHUNK) {
            const float* ep = emb + (size_t)(k0 + tid) * ED;
            float r[8];
#pragma unroll
            for (int j = 0; j < 8; ++j) r[j] = __fmul_rn(ep[j], ep[j]);
#pragma unroll
            for (int i = 8; i < 64; i += 8)
#pragma unroll
                for (int j = 0; j < 8; ++j)
                    r[j] = __fadd_rn(r[j], __fmul_rn(ep[i + j], ep[i + j]));
            s_esq[tid] = __fadd_rn(
                __fadd_rn(__fadd_rn(r[0], r[1]), __fadd_rn(r[2], r[3])),
                __fadd_rn(__fadd_rn(r[4], r[5]), __fadd_rn(r[6], r[7])));
        }
        __syncthreads();

        float acc[4][8];
#pragma unroll
        for (int mu = 0; mu < 4; ++mu)
#pragma unroll
            for (int ku = 0; ku < 8; ++ku) acc[mu][ku] = 0.f;

#pragma unroll 4
        for (int c = 0; c < 64; ++c) {
            int c4 = c >> 2;
            float4 av = *(const float4*)(s_a + c * 64 + mbase);
            float4 b0 = *(const float4*)(s_b + c * 132 + ((2 * ki + c4) & 31) * 4);
            float4 b1 = *(const float4*)(s_b + c * 132 + ((2 * ki + 1 + c4) & 31) * 4);
#pragma unroll
            for (int mu = 0; mu < 4; ++mu) {
                float a = (&av.x)[mu];
                acc[mu][0] = __fmaf_rn(a, b0.x, acc[mu][0]);
                acc[mu][1] = __fmaf_rn(a, b0.y, acc[mu][1]);
                acc[mu][2] = __fmaf_rn(a, b0.z, acc[mu][2]);
                acc[mu][3] = __fmaf_rn(a, b0.w, acc[mu][3]);
                acc[mu][4] = __fmaf_rn(a, b1.x, acc[mu][4]);
                acc[mu][5] = __fmaf_rn(a, b1.y, acc[mu][5]);
                acc[mu][6] = __fmaf_rn(a, b1.z, acc[mu][6]);
                acc[mu][7] = __fmaf_rn(a, b1.w, acc[mu][7]);
            }
        }

        // d = fl(fl(zsq+esq) - dot2); running per-thread argmin (k ascending)
#pragma unroll
        for (int mu = 0; mu < 4; ++mu)
#pragma unroll
            for (int ku = 0; ku < 8; ++ku) {
                float d = __fsub_rn(__fadd_rn(zs[mu], s_esq[kbase + ku]),
                                    acc[mu][ku]);
                if (d < bd[mu]) { bd[mu] = d; bix[mu] = k0 + kbase + ku; }
            }
    }

    // Merge 16 ki candidates per m with lexicographic (d, i) min ==
    // np.argmin lowest-index-among-minima. Reuse s_b as scratch.
    __syncthreads();
    float* red_d = s_b;               // [16][64]
    int* red_i = (int*)(s_b + 1024);  // [16][64]
#pragma unroll
    for (int mu = 0; mu < 4; ++mu) {
        red_d[ki * 64 + mbase + mu] = bd[mu];
        red_i[ki * 64 + mbase + mu] = bix[mu];
    }
    __syncthreads();
    if (tid < MT) {
        float best = red_d[tid];
        int bi = red_i[tid];
#pragma unroll
        for (int q = 1; q < 16; ++q) {
            float d = red_d[q * 64 + tid];
            int i = red_i[q * 64 + tid];
            if (d < best || (d == best && i < bi)) { best = d; bi = i; }
        }
        fidx[n0 + tid] = bi;
        out[O_IDX + n0 + tid] = (float)bi;
    }
}

// Gather-based segment sum: one block per code k, 4 waves. Ballot-scan idx;
// members accumulated lane=element; popcount -> cs. Deterministic. No atomics.
__global__ void __launch_bounds__(256) k_sumenc(const int* __restrict__ idx,
                                                const float* __restrict__ z,
                                                float* __restrict__ cs,
                                                float* __restrict__ sumenc) {
    int k = blockIdx.x;
    int wave = threadIdx.x >> 6, lane = threadIdx.x & 63;
    float acc = 0.f;
    int cnt = 0;
    int base = wave * 8192;
    for (int it = 0; it < 128; ++it) {
        int n0 = base + it * 64;
        int idv = idx[n0 + lane];
        unsigned long long m = __ballot(idv == k);
        cnt += __popcll(m);
        while (m) {
            int bit = __ffsll((unsigned long long)m) - 1;  // ascending n
            m &= m - 1;
            int n = n0 + bit;
            int b = n >> 10, hw = n & 1023;
            acc = __fadd_rn(acc, z[b * 65536 + lane * 1024 + hw]);  // element c = lane
        }
    }
    __shared__ float sacc[4][64];
    __shared__ int scnt[4];
    sacc[wave][lane] = acc;
    if (lane == 0) scnt[wave] = cnt;
    __syncthreads();
    if (wave == 0) {
        float t = __fadd_rn(__fadd_rn(sacc[0][lane], sacc[1][lane]),
                            __fadd_rn(sacc[2][lane], sacc[3][lane]));
        sumenc[k * ED + lane] = t;
        if (lane == 0) cs[k] = (float)(scnt[0] + scnt[1] + scnt[2] + scnt[3]);
    }
}

// Single block, 1024 threads: EMA cluster-size + ntot/entropy reductions +
// perplexity + codebook update. Fused.
__global__ void __launch_bounds__(1024) k_ema(const float* __restrict__ ema_cs,
                                              const float* __restrict__ ema_w,
                                              const float* __restrict__ cs,
                                              const float* __restrict__ sumenc,
                                              float* __restrict__ newemb,
                                              float* __restrict__ out) {
    int k = threadIdx.x;  // 0..1023 == NE
    float c = cs[k];
    float ncs = 0.99f * ema_cs[k] + (1.0f - 0.99f) * c;
    float p = c * (1.0f / (float)NVEC);
    float e = p * logf(p + 1e-10f);
    float rn_ = ncs, re_ = e;
#pragma unroll
    for (int o = 32; o > 0; o >>= 1) {
        rn_ += __shfl_down(rn_, o, 64);
        re_ += __shfl_down(re_, o, 64);
    }
    __shared__ float sn[16], se_[16];
    __shared__ float s_n;
    int wave = k >> 6, lane = k & 63;
    if (lane == 0) { sn[wave] = rn_; se_[wave] = re_; }
    __syncthreads();
    if (k == 0) {
        float tn = 0.f, te = 0.f;
#pragma unroll
        for (int w = 0; w < 16; ++w) { tn += sn[w]; te += se_[w]; }
        s_n = tn;
        out[O_PERP] = expf(-te);
    }
    __syncthreads();
    float nt = s_n;
    float csn = (ncs + 1e-5f) / (nt + 1024.0f * 1e-5f) * nt;
    __shared__ float s_csn[NE];
    s_csn[k] = csn;
    __syncthreads();
    for (int t = k; t < NE * ED; t += 1024) {  // coalesced
        float nw = 0.99f * ema_w[t] + (1.0f - 0.99f) * sumenc[t];
        newemb[t] = nw / s_csn[t >> 6];
    }
}

// 2048 blocks x 256 threads: z_q + straight-through + loss partials + one-hot
// rows (16/block, full 0..1023 coverage). Plain store per block; NO fences.
__global__ void __launch_bounds__(256) k_zq(const float* __restrict__ z,
                                            const int* __restrict__ idx,
                                            const float* __restrict__ newemb,
                                            float* __restrict__ out,
                                            float* __restrict__ lossp) {
    __shared__ int sbi[16];
    if (threadIdx.x < 16) sbi[threadIdx.x] = idx[blockIdx.x * 16 + threadIdx.x];
    __syncthreads();

    float local = 0.f;
#pragma unroll
    for (int i = 0; i < 4; ++i) {
        int t = blockIdx.x * 256 + threadIdx.x + i * 524288;
        int b = t >> 16, c = (t >> 10) & 63, hw = t & 1023;
        int n = (b << 10) | hw;
        float e = newemb[idx[n] * ED + c];
        float zv = z[t];
        float diff = e - zv;             // z_q - z
        out[O_ZQ + t] = zv + diff;       // straight-through: z + (z_q - z)
        local = fmaf(diff, diff, local);
    }

    // one-hot rows r0..r0+15 (row base ≡ 2 mod 4 floats; full coverage)
    int t = threadIdx.x;
    int r0 = blockIdx.x * 16;
    for (int r = 0; r < 16; ++r) {
        int rbi = sbi[r];
        float* rp = out + O_MINENC + (size_t)(r0 + r) * NE;
        if (t < 254) {
            int col = 2 + t * 4;
            float4 v;
            v.x = (col == rbi) ? 1.0f : 0.0f;
            v.y = (col + 1 == rbi) ? 1.0f : 0.0f;
            v.z = (col + 2 == rbi) ? 1.0f : 0.0f;
            v.w = (col + 3 == rbi) ? 1.0f : 0.0f;
            *(float4*)(rp + col) = v;
        } else if (t == 254) {
            float2 v;
            v.x = (0 == rbi) ? 1.0f : 0.0f;
            v.y = (1 == rbi) ? 1.0f : 0.0f;
            *(float2*)(rp) = v;
        } else {
            float4 v;
            v.x = (1018 == rbi) ? 1.0f : 0.0f;
            v.y = (1019 == rbi) ? 1.0f : 0.0f;
            v.z = (1020 == rbi) ? 1.0f : 0.0f;
            v.w = (1021 == rbi) ? 1.0f : 0.0f;
            *(float4*)(rp + 1018) = v;
            float2 w;
            w.x = (1022 == rbi) ? 1.0f : 0.0f;
            w.y = (1023 == rbi) ? 1.0f : 0.0f;
            *(float2*)(rp + 1022) = w;
        }
    }

#pragma unroll
    for (int o = 32; o > 0; o >>= 1) local += __shfl_down(local, o, 64);
    __shared__ float sp[4];
    int wave = threadIdx.x >> 6;
    if ((threadIdx.x & 63) == 0) sp[wave] = local;
    __syncthreads();
    if (threadIdx.x == 0)
        lossp[blockIdx.x] = (sp[0] + sp[1]) + (sp[2] + sp[3]);
}

// One block, 256 threads: reduce 2048 partials -> loss.
__global__ void __launch_bounds__(256) k_fin(const float* __restrict__ lossp,
                                             float* __restrict__ out) {
    float v = 0.f;
#pragma unroll
    for (int i = 0; i < 8; ++i) v += lossp[i * 256 + threadIdx.x];
#pragma unroll
    for (int o = 32; o > 0; o >>= 1) v += __shfl_down(v, o, 64);
    __shared__ float sp[4];
    int wave = threadIdx.x >> 6;
    if ((threadIdx.x & 63) == 0) sp[wave] = v;
    __syncthreads();
    if (threadIdx.x == 0)
        out[O_LOSS] = 0.25f * (((sp[0] + sp[1]) + (sp[2] + sp[3])) * (1.0f / (float)TOT));
}

extern "C" void kernel_launch(void* const* d_in, const int* in_sizes, int n_in,
                              void* d_out, int out_size, void* d_ws, size_t ws_size,
                              hipStream_t stream) {
    const float* z      = (const float*)d_in[0];
    const float* emb    = (const float*)d_in[1];
    const float* ema_cs = (const float*)d_in[2];
    const float* ema_w  = (const float*)d_in[3];
    float* out = (float*)d_out;
    float* ws  = (float*)d_ws;

    k_dist<<<512, 256, 0, stream>>>(z, emb, (int*)(ws + W_PIDX), out);
    k_sumenc<<<NE, 256, 0, stream>>>((const int*)(ws + W_PIDX), z, ws + W_CS,
                                     ws + W_SUMENC);
    k_ema<<<1, 1024, 0, stream>>>(ema_cs, ema_w, ws + W_CS, ws + W_SUMENC,
                                  ws + W_NEWEMB, out);
    k_zq<<<2048, 256, 0, stream>>>(z, (const int*)(ws + W_PIDX), ws + W_NEWEMB, out,
                                   ws + W_LOSSP);
    k_fin<<<1, 256, 0, stream>>>(ws + W_LOSSP, out);
}